// Round 16
// baseline (749.394 us; speedup 1.0000x reference)
//
#include <hip/hip_runtime.h>
#include <hip/hip_bf16.h>
#include <cstdint>

// B=4, S=4096, E=2048, H=16, D=128 -> 16384 independent tokens.
// qkv = x @ W_qkv (16384x2048x6144); per-token 16x16 head mix;
// out = attn @ W_out + b_out (16384x2048x2048).

#define TOKENS 16384
#define EMB    2048
#define NQKV   6144

typedef __bf16 bf16x8_t __attribute__((ext_vector_type(8)));
typedef float  f32x4_t  __attribute__((ext_vector_type(4)));
typedef unsigned short ushort8_t __attribute__((ext_vector_type(8)));

#define GLOAD16(gsrc, ldst)                                                    \
  __builtin_amdgcn_global_load_lds(                                            \
      (const __attribute__((address_space(1))) void*)(uintptr_t)(gsrc),        \
      (__attribute__((address_space(3))) void*)(uint32_t)(uintptr_t)(ldst),    \
      16, 0, 0)

static __device__ __forceinline__ unsigned short f32_to_bf16_bits(float f) {
  union { float f; uint32_t u; } x; x.f = f;
  uint32_t u = x.u;
  u += 0x7fffu + ((u >> 16) & 1u);   // round-to-nearest-even
  return (unsigned short)(u >> 16);
}

static __device__ __forceinline__ unsigned int pack_bf16(float lo, float hi) {
  return ((unsigned int)f32_to_bf16_bits(hi) << 16) | (unsigned int)f32_to_bf16_bits(lo);
}

// ------------------------------------------------- merged prep kernel
__global__ __launch_bounds__(256) void prep(
    const float4* __restrict__ x4, ushort4* __restrict__ xb4,
    const float* __restrict__ Wqkv, unsigned short* __restrict__ wqkvT,
    const float* __restrict__ Wout, unsigned short* __restrict__ woutT) {
  const int b = blockIdx.x;
  const int t = threadIdx.x;
  if (b < 2048) {
    const int n4 = 33554432 / 4;
    const int stride = 2048 * 256;
    for (int i = b * 256 + t; i < n4; i += stride) {
      float4 v = x4[i];
      ushort4 o;
      o.x = f32_to_bf16_bits(v.x);
      o.y = f32_to_bf16_bits(v.y);
      o.z = f32_to_bf16_bits(v.z);
      o.w = f32_to_bf16_bits(v.w);
      xb4[i] = o;
    }
    return;
  }
  __shared__ float tile[32][33];
  const float* in;
  unsigned short* out;
  int R, C, bxt, byt;
  if (b < 14336) {
    const int bb = b - 2048;
    in = Wqkv; out = wqkvT; R = 2048; C = 6144;
    bxt = bb % 192; byt = bb / 192;
  } else {
    const int bb = b - 14336;
    in = Wout; out = woutT; R = 2048; C = 2048;
    bxt = bb % 64; byt = bb / 64;
  }
  const int bx = bxt * 32;
  const int by = byt * 32;
  const int tx = t & 31;
  const int ty = t >> 5;   // 0..7
#pragma unroll
  for (int j = 0; j < 32; j += 8)
    tile[ty + j][tx] = in[(size_t)(by + ty + j) * C + bx + tx];
  __syncthreads();
#pragma unroll
  for (int j = 0; j < 32; j += 8)
    out[(size_t)(bx + ty + j) * R + by + tx] = f32_to_bf16_bits(tile[tx][ty + j]);
}

// ---------------------------------------------------------------- GEMM
// 128x128 tile, BK=64, 4 waves (2M x 2N), 256 threads, 64 KiB LDS ->
// TWO CO-RESIDENT BLOCKS PER CU. The R10 2-phase body (identical stage
// counts PhA=2/PhB=6, vmcnt(6) induction, WAR proofs, swizzle) ported to
// the smaller tile: while one block drains its barrier/lgkm, the other
// block's MFMAs issue (m114 cross-block overlap) -- the role-split that
// intra-block schedules could not achieve (R9/R13 nulls).
template <bool OUT_BF16>
__global__ __launch_bounds__(256, 2) void gemm_bt(
    const unsigned short* __restrict__ A,
    const unsigned short* __restrict__ BT,
    unsigned short* __restrict__ Cb,
    float* __restrict__ Cf,
    const float* __restrict__ bias,
    int M, int N) {
  constexpr int K = 2048;
  constexpr int BK = 64;
  constexpr int NKT = K / BK;          // 32
  __shared__ __align__(16) char lds[65536];  // [2 bufs][A 16KB | B 16KB]

  const int nbx = N / 128;
  const int nwg = gridDim.x;           // % 8 == 0
  const int bid = blockIdx.x;
  const int swzb = (bid & 7) * (nwg >> 3) + (bid >> 3);
  const int by = swzb / nbx;
  const int bx = swzb % nbx;

  const int t    = threadIdx.x;
  const int lane = t & 63;
  const int wid  = t >> 6;             // 0..3
  const int wr   = wid >> 1;           // 0..1 (M)
  const int wc   = wid & 1;            // 0..1 (N)
  const int lr   = lane & 15;
  const int g    = lane >> 4;          // 0..3

  const unsigned short* aSrc = A  + (size_t)by * 128 * K;
  const unsigned short* bSrc = BT + (size_t)bx * 128 * K;

  // staging source offsets (inverse-swizzled global, linear LDS dest)
  // A half (64 rows, 8KB): 2 instrs; B full (128 rows, 16KB): 4 instrs.
  int ahoff[2], bfoff[4];
#pragma unroll
  for (int i = 0; i < 2; ++i) {
    const int p   = (i * 256 + t) * 16;          // [0, 8192)
    const int lo  = p ^ (((p >> 7) & 7) << 4);
    ahoff[i] = (lo >> 7) * K + ((lo & 127) >> 1);
  }
#pragma unroll
  for (int i = 0; i < 4; ++i) {
    const int p   = (i * 256 + t) * 16;          // [0, 16384)
    const int lo  = p ^ (((p >> 7) & 7) << 4);
    bfoff[i] = (lo >> 7) * K + ((lo & 127) >> 1);
  }
  const int ldst = wid << 10;

  auto stageA = [&](int h, int k0, char* bufA) {
#pragma unroll
    for (int i = 0; i < 2; ++i)
      GLOAD16(aSrc + ahoff[i] + h * (64 * K) + k0, bufA + h * 8192 + i * 4096 + ldst);
  };
  auto stageB = [&](int k0, char* bufB) {
#pragma unroll
    for (int i = 0; i < 4; ++i)
      GLOAD16(bSrc + bfoff[i] + k0, bufB + i * 4096 + ldst);
  };

  // swizzled ds_read addresses (row stride 128B, same swizzle as R10)
  const int sw   = (lr & 7) << 4;
  const int col0 = (g * 16) ^ sw;
  const int col1 = (64 + g * 16) ^ sw;
  const int aRow = (wr * 64 + lr) * 128;
  const int bRow = (wc * 64 + lr) * 128;

  f32x4_t acc[4][4] = {};
  bf16x8_t av[4][2];                   // A frags [mf][ks]
  bf16x8_t bv[4][2];                   // B frags [nf][ks]

#define LDA_ALL(cA_)                                                           \
  _Pragma("unroll") for (int mf = 0; mf < 4; ++mf) {                           \
    av[mf][0] = *(const bf16x8_t*)((cA_) + aRow + mf * 2048 + col0);           \
    av[mf][1] = *(const bf16x8_t*)((cA_) + aRow + mf * 2048 + col1);           \
  }
#define LDB_ALL(cB_)                                                           \
  _Pragma("unroll") for (int nf = 0; nf < 4; ++nf) {                           \
    bv[nf][0] = *(const bf16x8_t*)((cB_) + bRow + nf * 2048 + col0);           \
    bv[nf][1] = *(const bf16x8_t*)((cB_) + bRow + nf * 2048 + col1);           \
  }
#define MFMA_NF(NF0)                                                           \
  _Pragma("unroll") for (int mf = 0; mf < 4; ++mf)                             \
  _Pragma("unroll") for (int nf = (NF0); nf < (NF0) + 2; ++nf)                 \
  _Pragma("unroll") for (int ks = 0; ks < 2; ++ks)                             \
    acc[mf][nf] = __builtin_amdgcn_mfma_f32_16x16x32_bf16(                     \
        av[mf][ks], bv[nf][ks], acc[mf][nf], 0, 0, 0);

#define SBR __builtin_amdgcn_sched_barrier(0)

  // One K-tile: 2 phases, 2 barriers, 1 lgkm drain, 1 counted vmcnt.
#define BODY(KT, S1, S2, VMN)                                                  \
  {                                                                            \
    char* cA = lds + ((KT) & 1) * 32768;                                       \
    char* cB = cA + 16384;                                                     \
    char* nA = lds + (((KT) + 1) & 1) * 32768;                                 \
    const int k1 = ((KT) + 1) * BK, k2 = ((KT) + 2) * BK;                      \
    /* PhA: all 16 reads (covered by prev PhB vmcnt->barrier); stage           \
       Ah1(kt+1) (readers drained 2 barriers back); drain; MFMA nf0-1 */       \
    LDA_ALL(cA);                                                               \
    LDB_ALL(cB); SBR;                                                          \
    if (S1) { stageA(1, k1, nA); } SBR;                                        \
    asm volatile("s_waitcnt lgkmcnt(0)" ::: "memory"); SBR;                    \
    __builtin_amdgcn_s_setprio(1);                                             \
    MFMA_NF(0);                                                                \
    __builtin_amdgcn_s_setprio(0); SBR;                                        \
    __builtin_amdgcn_s_barrier();                                              \
    /* PhB: stage (kt+2) into CURRENT bufs (readers drained at PhA lgkm,       \
       PhA barrier separates -> WAR-safe); MFMA nf2-3; vmcnt(6); barrier */    \
    if (S2) { stageB(k2, cB); stageA(0, k2, cA); } SBR;                        \
    __builtin_amdgcn_s_setprio(1);                                             \
    MFMA_NF(2);                                                                \
    __builtin_amdgcn_s_setprio(0); SBR;                                        \
    asm volatile("s_waitcnt vmcnt(" #VMN ")" ::: "memory"); SBR;               \
    __builtin_amdgcn_s_barrier();                                              \
  }

  // ---- prologue: tile0 (8 instrs) + tile1 {B(4), Ah0(2)}; vmcnt(6) =
  // tile0 landed; barrier -> BODY(0) PhA reads formally covered.
  {
    char* b0A = lds;
    char* b0B = lds + 16384;
    char* b1A = lds + 32768;
    char* b1B = b1A + 16384;
    stageA(0, 0, b0A); stageA(1, 0, b0A);
    stageB(0, b0B);
    stageB(BK, b1B);
    stageA(0, BK, b1A);
    asm volatile("s_waitcnt vmcnt(6)" ::: "memory");
    __builtin_amdgcn_s_barrier();
  }

  for (int kt = 0; kt < NKT - 2; ++kt) {
    BODY(kt, 1, 1, 6);
  }
  BODY(NKT - 2, 1, 0, 0);
  BODY(NKT - 1, 0, 0, 0);

  // ---- epilogue: C/D map col=lane&15, row=(lane>>4)*4+j
  const int rbase = by * 128 + wr * 64 + g * 4;
  const int cbase = bx * 128 + wc * 64 + lr;
#pragma unroll
  for (int mf = 0; mf < 4; ++mf) {
#pragma unroll
    for (int nf = 0; nf < 4; ++nf) {
      const int col = cbase + nf * 16;
#pragma unroll
      for (int j = 0; j < 4; ++j) {
        const size_t off = (size_t)(rbase + mf * 16 + j) * N + col;
        if constexpr (OUT_BF16) {
          Cb[off] = f32_to_bf16_bits(acc[mf][nf][j]);
        } else {
          Cf[off] = acc[mf][nf][j] + bias[col];
        }
      }
    }
  }
#undef LDA_ALL
#undef LDB_ALL
#undef MFMA_NF
#undef SBR
#undef BODY
}

// ---------------------------------------------------------------- attention
// MFMA attention: one wave per token, no barriers (R15, verified).
__global__ __launch_bounds__(256) void attn_mfma(
    const unsigned short* __restrict__ qkv,  // [T][6144] bf16
    unsigned short* __restrict__ attn) {     // [T][2048] bf16
  __shared__ __align__(16) unsigned short sV[4][2048];  // 4 waves x 4KB

  const int t  = threadIdx.x;
  const int w  = t >> 6;
  const int l  = t & 63;
  const int lr = l & 15;
  const int g  = l >> 4;           // 0..3
  const size_t tok = (size_t)blockIdx.x * 4 + w;
  const unsigned short* base = qkv + tok * NQKV;

  // ---- stage V (16x128) to LDS, word-swapped for H>=8 (read-swizzle match)
  {
    const uint4* vg = (const uint4*)(base + 4096);
    uint4* vl = (uint4*)&sV[w][0];
#pragma unroll
    for (int i = 0; i < 4; ++i) {
      const int idx = i * 64 + l;        // 256 uint4 = 16 rows x 16
      uint4 v = vg[idx];
      if (idx & 128) {                   // H = idx>>4; H&8 <=> idx&128
        uint4 o; o.x = v.y; o.y = v.x; o.z = v.w; o.w = v.z;
        vl[idx] = o;
      } else {
        vl[idx] = v;
      }
    }
  }

  // ---- QK^T -> S^T fragment (col=h=lr, row=H=g*4+r)
  f32x4_t s = {};
#pragma unroll
  for (int ch = 0; ch < 4; ++ch) {
    bf16x8_t ka = *(const bf16x8_t*)(base + 2048 + lr * 128 + ch * 32 + g * 8);
    bf16x8_t qb = *(const bf16x8_t*)(base +        lr * 128 + ch * 32 + g * 8);
    s = __builtin_amdgcn_mfma_f32_16x16x32_bf16(ka, qb, s, 0, 0, 0);
  }

  // ---- softmax over H (regs + lanes l^16, l^32); P unnormalized (<=1)
  float p0 = s[0] * 0.08838834764831843f;
  float p1 = s[1] * 0.08838834764831843f;
  float p2 = s[2] * 0.08838834764831843f;
  float p3 = s[3] * 0.08838834764831843f;
  float mx = fmaxf(fmaxf(p0, p1), fmaxf(p2, p3));
  mx = fmaxf(mx, __shfl_xor(mx, 16));
  mx = fmaxf(mx, __shfl_xor(mx, 32));
  p0 = __expf(p0 - mx);
  p1 = __expf(p1 - mx);
  p2 = __expf(p2 - mx);
  p3 = __expf(p3 - mx);
  float sum = p0 + p1 + p2 + p3;
  sum += __shfl_xor(sum, 16);
  sum += __shfl_xor(sum, 32);
  const float inv = 1.0f / sum;

  // ---- distribute P^T into B-frag layout: lane needs P[h=lr][H=g*8+jj]
  const unsigned int u01 = pack_bf16(p0, p1);
  const unsigned int u23 = pack_bf16(p2, p3);
  const int gs = (g & 1) * 2;
  const int m1 = (gs << 4) | lr;
  const int m2 = m1 + 16;
  union { uint4 u; bf16x8_t b; } pB;
  pB.u.x = __shfl(u01, m1);
  pB.u.y = __shfl(u23, m1);
  pB.u.z = __shfl(u01, m2);
  pB.u.w = __shfl(u23, m2);
  if (g >= 2) { pB.u.x = 0; pB.u.y = 0; pB.u.z = 0; pB.u.w = 0; }

  // ---- PV: 8 d-chunks; A = V^T frag (8 swizzled u16, zero for g>=2)
  const char* vbase = (const char*)&sV[w][0];
  const int dbyte = (lr * 2) ^ (g < 2 ? (g << 2) : 0);
#pragma unroll
  for (int ch = 0; ch < 8; ++ch) {
    union { ushort8_t u; bf16x8_t b; } va;
    if (g < 2) {
#pragma unroll
      for (int j = 0; j < 8; ++j) {
        const int H = g * 8 + j;
        va.u[j] = *(const unsigned short*)(vbase + H * 256 + ch * 32 + dbyte);
      }
    } else {
      va.u = (ushort8_t){0, 0, 0, 0, 0, 0, 0, 0};
    }
    f32x4_t z = {};
    f32x4_t o = __builtin_amdgcn_mfma_f32_16x16x32_bf16(va.b, pB.b, z, 0, 0, 0);
    uint2 st;
    st.x = pack_bf16(o[0] * inv, o[1] * inv);
    st.y = pack_bf16(o[2] * inv, o[3] * inv);
    *(uint2*)(attn + tok * EMB + lr * 128 + ch * 16 + g * 4) = st;
  }
}

// ---------------------------------------------------------------- launch
extern "C" void kernel_launch(void* const* d_in, const int* in_sizes, int n_in,
                              void* d_out, int out_size, void* d_ws, size_t ws_size,
                              hipStream_t stream) {
  const float* x    = (const float*)d_in[0];
  const float* Wqkv = (const float*)d_in[1];
  const float* Wout = (const float*)d_in[2];
  const float* bout = (const float*)d_in[3];
  float* out = (float*)d_out;

  unsigned short* xb    = (unsigned short*)d_ws;          // 33,554,432
  unsigned short* wqkvT = xb    + (size_t)33554432;       // 12,582,912
  unsigned short* woutT = wqkvT + (size_t)12582912;       //  4,194,304
  unsigned short* qkv   = woutT + (size_t)4194304;        // 100,663,296
  unsigned short* attn  = qkv   + (size_t)100663296;      // 33,554,432

  prep<<<18432, 256, 0, stream>>>((const float4*)x, (ushort4*)xb,
                                  Wqkv, wqkvT, Wout, woutT);
  // qkv = x @ W_qkv : grid 128*48 = 6144 (%8==0), 2 blocks/CU co-resident
  gemm_bt<true><<<(16384 / 128) * (6144 / 128), 256, 0, stream>>>(
      xb, wqkvT, qkv, nullptr, nullptr, 16384, 6144);
  // per-token head mixing: 1 wave per token, 4 tokens per block
  attn_mfma<<<TOKENS / 4, 256, 0, stream>>>(qkv, attn);
  // out = attn @ W_out + b_out : grid 128*16 = 2048 (%8==0)
  gemm_bt<false><<<(16384 / 128) * (2048 / 128), 256, 0, stream>>>(
      attn, woutT, nullptr, out, bout, 16384, 2048);
}